// Round 4
// baseline (536.113 us; speedup 1.0000x reference)
//
#include <hip/hip_runtime.h>
#include <hip/hip_bf16.h>
#include <math.h>

// Problem constants (from setup_inputs)
#define BB 8
#define QN 512
#define SN 64
#define TN 128
#define DD 128
#define STAT_K 8
#define TOK_K 16
#define SCALE 0.08838834764831845f   // 1/sqrt(128)
#define NEGBIG -1e6f
#define NINF  -3.4e38f

typedef float f4 __attribute__((ext_vector_type(4)));
typedef unsigned long long u64;

// Monotone-packed selection key: (value asc-mapped uint) <<32 | (127 - t).
// Larger key == (larger value, or equal value with smaller t) — exact jax
// top_k order (descending value, lowest index wins ties).
__device__ __forceinline__ u64 packkey(float x, int t) {
    unsigned u = __float_as_uint(x);
    u = (u & 0x80000000u) ? ~u : (u | 0x80000000u);
    return ((u64)u << 32) | (unsigned)(127 - t);
}
__device__ __forceinline__ float keyval(u64 k) {
    unsigned u = (unsigned)(k >> 32);
    u = (u & 0x80000000u) ? (u & 0x7fffffffu) : ~u;
    return __uint_as_float(u);
}

// compare-exchange keeping larger in a (descending)
#define CE_DESC(a, b) { bool sw_ = (a) < (b); u64 t_ = sw_ ? (b) : (a); (b) = sw_ ? (a) : (b); (a) = t_; }

// ---------------------------------------------------------------------------
// LDS-free GEMM tile: C[128,128-block] = A @ W, W read from L1/L2 (broadcast
// pattern, 64 KB, cache-resident). 256 threads, 8x8 per-thread tile.
// ---------------------------------------------------------------------------
__device__ __forceinline__ void proj_tile8_g(const float* __restrict__ A,
                                             const float* __restrict__ W,
                                             float* __restrict__ C,
                                             int blk, int transposed, int tid)
{
    const int tx = tid & 15;    // cols tx*4..+3 and 64+tx*4..+3
    const int ty = tid >> 4;    // rows ty*8..+7
    const size_t rowBase = (size_t)blk * 128;
    const float* Ab = A + (rowBase + ty * 8) * 128;

    float acc[8][8];
    #pragma unroll
    for (int i = 0; i < 8; ++i)
        #pragma unroll
        for (int j = 0; j < 8; ++j) acc[i][j] = 0.f;

    #pragma unroll 2
    for (int k0 = 0; k0 < 128; k0 += 4) {
        f4 a[8];
        #pragma unroll
        for (int i = 0; i < 8; ++i)
            a[i] = *(const f4*)(Ab + i * 128 + k0);        // 16-lane broadcast
        f4 wl[4], wh[4];
        #pragma unroll
        for (int kk = 0; kk < 4; ++kk) {
            wl[kk] = *(const f4*)(W + (k0 + kk) * 128 + tx * 4);
            wh[kk] = *(const f4*)(W + (k0 + kk) * 128 + 64 + tx * 4);
        }
        #pragma unroll
        for (int i = 0; i < 8; ++i)
            #pragma unroll
            for (int kk = 0; kk < 4; ++kk)
                #pragma unroll
                for (int j = 0; j < 4; ++j) {
                    acc[i][j]     = fmaf(a[i][kk], wl[kk][j], acc[i][j]);
                    acc[i][4 + j] = fmaf(a[i][kk], wh[kk][j], acc[i][4 + j]);
                }
    }

    if (!transposed) {
        #pragma unroll
        for (int i = 0; i < 8; ++i) {
            size_t row = rowBase + ty * 8 + i;
            f4 lo = {acc[i][0], acc[i][1], acc[i][2], acc[i][3]};
            f4 hi = {acc[i][4], acc[i][5], acc[i][6], acc[i][7]};
            *(f4*)&C[row * 128 + tx * 4]      = lo;
            *(f4*)&C[row * 128 + 64 + tx * 4] = hi;
        }
    } else {
        float* Cb = C + ((size_t)blk << 14);   // per-(b,s) [d][t] block
        #pragma unroll
        for (int j = 0; j < 4; ++j) {
            int clo = tx * 4 + j;
            int chi = 64 + tx * 4 + j;
            f4 v0 = {acc[0][j], acc[1][j], acc[2][j], acc[3][j]};
            f4 v1 = {acc[4][j], acc[5][j], acc[6][j], acc[7][j]};
            *(f4*)&Cb[clo * 128 + ty * 8]     = v0;
            *(f4*)&Cb[clo * 128 + ty * 8 + 4] = v1;
            f4 v2 = {acc[0][4 + j], acc[1][4 + j], acc[2][4 + j], acc[3][4 + j]};
            f4 v3 = {acc[4][4 + j], acc[5][4 + j], acc[6][4 + j], acc[7][4 + j]};
            *(f4*)&Cb[chi * 128 + ty * 8]     = v2;
            *(f4*)&Cb[chi * 128 + ty * 8 + 4] = v3;
        }
    }
}

// All five input projections in one launch (big ones first).
__global__ __launch_bounds__(256) void proj_all(const float* __restrict__ queries,
                                                const float* __restrict__ stat_keys,
                                                const float* __restrict__ token_keys,
                                                const float* __restrict__ values,
                                                const float* __restrict__ Wq_stat,
                                                const float* __restrict__ Wq_token,
                                                const float* __restrict__ Wk_stat,
                                                const float* __restrict__ Wk_token,
                                                const float* __restrict__ Wv,
                                                float* __restrict__ q_stat,
                                                float* __restrict__ q_tok,
                                                float* __restrict__ k_stat,
                                                float* __restrict__ kT,
                                                float* __restrict__ v)
{
    const int bi = blockIdx.x;
    if (bi < 512)        proj_tile8_g(token_keys, Wk_token, kT,     bi,        1, threadIdx.x);
    else if (bi < 1024)  proj_tile8_g(values,     Wv,       v,      bi - 512,  0, threadIdx.x);
    else if (bi < 1056)  proj_tile8_g(queries,    Wq_stat,  q_stat, bi - 1024, 0, threadIdx.x);
    else if (bi < 1088)  proj_tile8_g(queries,    Wq_token, q_tok,  bi - 1056, 0, threadIdx.x);
    else                 proj_tile8_g(stat_keys,  Wk_stat,  k_stat, bi - 1088, 0, threadIdx.x);
}

// Output projection, 64 rows/block (small tail kernel -> more blocks).
__global__ __launch_bounds__(256) void proj_out(const float* __restrict__ A,
                                                const float* __restrict__ W,
                                                float* __restrict__ C)
{
    const int tid = threadIdx.x;
    const int tx = tid & 15;
    const int ty = tid >> 4;
    const int rowBase = blockIdx.x * 64 + ty * 4;
    const float* Ab = A + (size_t)rowBase * 128;

    float acc[4][8];
    #pragma unroll
    for (int i = 0; i < 4; ++i)
        #pragma unroll
        for (int j = 0; j < 8; ++j) acc[i][j] = 0.f;

    #pragma unroll 2
    for (int k0 = 0; k0 < 128; k0 += 4) {
        f4 a[4];
        #pragma unroll
        for (int i = 0; i < 4; ++i)
            a[i] = *(const f4*)(Ab + i * 128 + k0);
        f4 wl[4], wh[4];
        #pragma unroll
        for (int kk = 0; kk < 4; ++kk) {
            wl[kk] = *(const f4*)(W + (k0 + kk) * 128 + tx * 4);
            wh[kk] = *(const f4*)(W + (k0 + kk) * 128 + 64 + tx * 4);
        }
        #pragma unroll
        for (int i = 0; i < 4; ++i)
            #pragma unroll
            for (int kk = 0; kk < 4; ++kk)
                #pragma unroll
                for (int j = 0; j < 4; ++j) {
                    acc[i][j]     = fmaf(a[i][kk], wl[kk][j], acc[i][j]);
                    acc[i][4 + j] = fmaf(a[i][kk], wh[kk][j], acc[i][4 + j]);
                }
    }
    #pragma unroll
    for (int i = 0; i < 4; ++i) {
        size_t row = (size_t)rowBase + i;
        f4 lo = {acc[i][0], acc[i][1], acc[i][2], acc[i][3]};
        f4 hi = {acc[i][4], acc[i][5], acc[i][6], acc[i][7]};
        *(f4*)&C[row * 128 + tx * 4]      = lo;
        *(f4*)&C[row * 128 + 64 + tx * 4] = hi;
    }
}

// ---------------------------------------------------------------------------
// Stat level: one wave per (b,q), lane = stat s. Top-8 + softmax (exact jax
// tie-break: lowest index). Invalid stats -> exp underflows to exactly 0.
// ---------------------------------------------------------------------------
__global__ __launch_bounds__(64, 4) void stat_topk(const float* __restrict__ qs,
                                                   const float* __restrict__ ks,
                                                   const int* __restrict__ vlen,
                                                   int* __restrict__ sel_i,
                                                   float* __restrict__ sel_w)
{
    const int bq   = blockIdx.x;
    const int b    = bq >> 9;
    const int lane = threadIdx.x;

    const f4* q4 = (const f4*)(qs + (size_t)bq * 128);
    const f4* k4 = (const f4*)(ks + (size_t)(b * SN + lane) * 128);
    float acc = 0.f;
    #pragma unroll 8
    for (int kk = 0; kk < 32; ++kk) {
        f4 q = q4[kk];
        f4 k = k4[kk];
        acc = fmaf(q[0], k[0], acc);
        acc = fmaf(q[1], k[1], acc);
        acc = fmaf(q[2], k[2], acc);
        acc = fmaf(q[3], k[3], acc);
    }
    float score = acc * SCALE;
    if (lane >= vlen[b]) score = NEGBIG;

    float work = score;
    float tv[STAT_K];
    int   ti[STAT_K];
    #pragma unroll
    for (int j = 0; j < STAT_K; ++j) {
        float m = work;
        #pragma unroll
        for (int off = 32; off > 0; off >>= 1) m = fmaxf(m, __shfl_xor(m, off));
        unsigned long long ball = __ballot(work == m);
        int L = __ffsll(ball) - 1;     // lowest index wins ties
        tv[j] = m;
        ti[j] = L;
        if (lane == L) work = NINF;
    }

    float w[STAT_K];
    float Z = 0.f;
    #pragma unroll
    for (int j = 0; j < STAT_K; ++j) { w[j] = expf(tv[j] - tv[0]); Z += w[j]; }
    float invZ = 1.f / Z;

    if (lane < STAT_K) {
        sel_i[(size_t)bq * STAT_K + lane] = ti[lane];
        sel_w[(size_t)bq * STAT_K + lane] = w[lane] * invZ;
    }
}

// ---------------------------------------------------------------------------
__global__ void zero_misc(float* __restrict__ out_pre, int* __restrict__ cnt)
{
    int idx = blockIdx.x * 256 + threadIdx.x;    // 512*256 = 131072 f4 = 2 MB
    f4 z = {0.f, 0.f, 0.f, 0.f};
    ((f4*)out_pre)[idx] = z;
    if (idx < BB * SN) cnt[idx] = 0;
}

__global__ void bin_build(const int* __restrict__ sel_i,
                          const float* __restrict__ sel_w,
                          int* __restrict__ cnt, int* __restrict__ list)
{
    int idx = blockIdx.x * 256 + threadIdx.x;    // bq*8+si, 32768 total
    if (idx >= BB * QN * STAT_K) return;
    float sw = sel_w[idx];
    if (sw == 0.f) return;                       // exactly-zero contribution
    int bq = idx >> 3, si = idx & 7;
    int b = bq >> 9, q = bq & 511;
    int s = sel_i[idx];
    int bs = b * SN + s;
    int pos = atomicAdd(&cnt[bs], 1);
    list[bs * 512 + pos] = q | (si << 16);
}

// ---------------------------------------------------------------------------
// Token level: 4 waves/block, each wave owns a 16-query chunk of one bin.
// Phase A: GEMM scores (k from L2) -> 8 KB LDS tile [128t][16q], XOR-swizzled.
// Phase B: lane=(q,quarter): top-16-of-32 insertion on packed u64 keys,
//          then exact bitonic merge across quarters via 2 shfl_xor levels.
// Phase C: per-(q,quarter) v gather over d-quarter, atomicAdd into out_pre.
// ---------------------------------------------------------------------------
__global__ __launch_bounds__(256) void tok_fused(const float* __restrict__ qt,
                                                 const float* __restrict__ kT,
                                                 const float* __restrict__ v,
                                                 const int* __restrict__ cnt,
                                                 const int* __restrict__ list,
                                                 const float* __restrict__ sel_w,
                                                 float* __restrict__ out_pre)
{
    const int bin = blockIdx.x & 511;
    const int cg  = blockIdx.x >> 9;       // 0..7
    const int b   = bin & 7;               // batch fast -> XCD spread
    const int s   = bin >> 3;
    const int bs  = b * SN + s;
    const int nq  = cnt[bs];

    const int tid  = threadIdx.x;
    const int wid  = tid >> 6;
    const int lane = tid & 63;
    const int q0   = (cg * 4 + wid) * 16;
    if (q0 >= nq) return;
    const int nhere = min(16, nq - q0);

    __shared__ float sl[4][128 * 16];      // 32 KB total, 8 KB per wave
    float* slw = sl[wid];

    // ---- Phase A: scores [128t][16q] ----
    const int qg = lane >> 5;              // 8-query group
    const int tg = lane & 31;              // tokens tg*4..tg*4+3
    const float* kb = kT + ((size_t)bs << 14);

    int qrow[8];
    #pragma unroll
    for (int i = 0; i < 8; ++i) {
        int e = list[bs * 512 + min(q0 + qg * 8 + i, nq - 1)];  // clamp: dup row
        qrow[i] = e & 0xffff;
    }

    float acc[8][4];
    #pragma unroll
    for (int i = 0; i < 8; ++i)
        #pragma unroll
        for (int j = 0; j < 4; ++j) acc[i][j] = 0.f;

    #pragma unroll 2
    for (int dq = 0; dq < 128; dq += 4) {
        f4 kf[4];
        #pragma unroll
        for (int kk = 0; kk < 4; ++kk)
            kf[kk] = *(const f4*)(kb + (size_t)(dq + kk) * 128 + tg * 4);
        f4 qv[8];
        #pragma unroll
        for (int i = 0; i < 8; ++i)
            qv[i] = *(const f4*)(qt + ((size_t)(b * QN + qrow[i])) * 128 + dq);
        #pragma unroll
        for (int i = 0; i < 8; ++i)
            #pragma unroll
            for (int kk = 0; kk < 4; ++kk)
                #pragma unroll
                for (int j = 0; j < 4; ++j)
                    acc[i][j] = fmaf(qv[i][kk], kf[kk][j], acc[i][j]);
    }
    // store swizzled: col = q ^ ((t>>2)&15)
    #pragma unroll
    for (int i = 0; i < 8; ++i)
        #pragma unroll
        for (int j = 0; j < 4; ++j) {
            int t = tg * 4 + j;
            int q = qg * 8 + i;
            slw[t * 16 + (q ^ (tg & 15))] = acc[i][j] * SCALE;
        }

    // same-wave LDS producer->consumer: LDS pipe is in-order per wave; just
    // stop the compiler from reordering.
    __asm__ __volatile__("" ::: "memory");
    __builtin_amdgcn_wave_barrier();
    __asm__ __volatile__("" ::: "memory");

    // ---- Phase B: lane = (q, quarter); top-16 of 32 interleaved tokens ----
    const int q       = lane & 15;
    const int quarter = lane >> 4;

    u64 key[16];
    #pragma unroll
    for (int j = 0; j < 16; ++j) key[j] = 0ull;   // < any real packed key

    #pragma unroll 4
    for (int i = 0; i < 32; ++i) {
        int t = i * 4 + quarter;                   // t>>2 == i
        float x = slw[t * 16 + (q ^ (i & 15))];
        u64 k = packkey(x, t);
        #pragma unroll
        for (int j = 0; j < 16; ++j) {
            bool sw = k > key[j];
            u64 hi = sw ? k : key[j];
            k      = sw ? key[j] : k;
            key[j] = hi;
        }
    }

    // merge across quarters: xor 16 (q0<->q1, q2<->q3), then xor 32
    #pragma unroll
    for (int lev = 0; lev < 2; ++lev) {
        const int d = 16 << lev;
        u64 other[16];
        #pragma unroll
        for (int j = 0; j < 16; ++j) other[j] = __shfl_xor(key[j], d);
        // bitonic split: top-16 of the 32-element union (bitonic sequence)
        #pragma unroll
        for (int j = 0; j < 16; ++j) {
            u64 o = other[15 - j];
            key[j] = key[j] > o ? key[j] : o;
        }
        // bitonic sort (descending) of the 16 survivors
        #pragma unroll
        for (int j = 0; j < 16; ++j) if (!(j & 8)) CE_DESC(key[j], key[j + 8]);
        #pragma unroll
        for (int j = 0; j < 16; ++j) if (!(j & 4)) CE_DESC(key[j], key[j + 4]);
        #pragma unroll
        for (int j = 0; j < 16; ++j) if (!(j & 2)) CE_DESC(key[j], key[j + 2]);
        #pragma unroll
        for (int j = 0; j < 16; ++j) if (!(j & 1)) CE_DESC(key[j], key[j + 1]);
    }
    // all 4 quarter-lanes of a q now hold identical sorted top-16

    // ---- softmax + Phase C: PV over d-quarter ----
    float pw[TOK_K];
    int   tt[TOK_K];
    float mx = keyval(key[0]);
    float Z = 0.f;
    #pragma unroll
    for (int j = 0; j < TOK_K; ++j) {
        pw[j] = expf(keyval(key[j]) - mx);
        Z += pw[j];
        tt[j] = 127 - (int)(key[j] & 127u);
    }

    if (q < nhere) {
        int e = list[bs * 512 + q0 + q];
        int qrow2 = e & 0xffff;
        int sidx  = (e >> 16) & 7;
        float sww = sel_w[((size_t)(b * QN + qrow2)) * STAT_K + sidx];
        float cs  = sww / Z;                       // fold stat weight in

        const float* vb = v + ((size_t)bs << 14) + quarter * 32;
        f4 o[8];
        #pragma unroll
        for (int c = 0; c < 8; ++c) o[c] = (f4){0.f, 0.f, 0.f, 0.f};
        #pragma unroll
        for (int j = 0; j < TOK_K; ++j) {
            float w = pw[j] * cs;
            const f4* vr = (const f4*)(vb + (size_t)tt[j] * 128);
            #pragma unroll
            for (int c = 0; c < 8; ++c) {
                f4 x = vr[c];
                o[c][0] = fmaf(w, x[0], o[c][0]);
                o[c][1] = fmaf(w, x[1], o[c][1]);
                o[c][2] = fmaf(w, x[2], o[c][2]);
                o[c][3] = fmaf(w, x[3], o[c][3]);
            }
        }
        float* op = out_pre + ((size_t)(b * QN + qrow2)) * 128 + quarter * 32;
        #pragma unroll
        for (int c = 0; c < 8; ++c) {
            atomicAdd(op + c * 4 + 0, o[c][0]);
            atomicAdd(op + c * 4 + 1, o[c][1]);
            atomicAdd(op + c * 4 + 2, o[c][2]);
            atomicAdd(op + c * 4 + 3, o[c][3]);
        }
    }
}

// ---------------------------------------------------------------------------
extern "C" void kernel_launch(void* const* d_in, const int* in_sizes, int n_in,
                              void* d_out, int out_size, void* d_ws, size_t ws_size,
                              hipStream_t stream)
{
    const float* queries    = (const float*)d_in[0];
    const float* stat_keys  = (const float*)d_in[1];
    const float* token_keys = (const float*)d_in[2];
    const float* values     = (const float*)d_in[3];
    const int*   vlen       = (const int*)d_in[4];
    const float* Wq_stat    = (const float*)d_in[5];
    const float* Wq_token   = (const float*)d_in[6];
    const float* Wk_stat    = (const float*)d_in[7];
    const float* Wk_token   = (const float*)d_in[8];
    const float* Wv         = (const float*)d_in[9];
    const float* Wo         = (const float*)d_in[10];

    char* ws = (char*)d_ws;
    float* q_stat  = (float*)(ws);                 // 2 MB (dead after stat_topk)
    int*   list    = (int*)  (ws);                 // 1 MB, overlays q_stat
    float* q_tok   = (float*)(ws + 2097152);       // 2 MB
    float* k_stat  = (float*)(ws + 4194304);       // 256 KB (dead after stat_topk)
    int*   cnt     = (int*)  (ws + 4194304);       // 2 KB, overlays k_stat
    float* k_tokT  = (float*)(ws + 4456448);       // [512][128d][128t] = 32 MB
    float* v       = (float*)(ws + 38010880);      // 32 MB
    int*   sel_i   = (int*)  (ws + 71565312);      // 128 KB
    float* sel_w   = (float*)(ws + 71696384);      // 128 KB
    float* out_pre = (float*)(ws + 71827456);      // 2 MB  (total 73,924,608 B)

    // All input projections (fp32 exact: scores feed top-k), one launch
    proj_all<<<1092, 256, 0, stream>>>(queries, stat_keys, token_keys, values,
                                       Wq_stat, Wq_token, Wk_stat, Wk_token, Wv,
                                       q_stat, q_tok, k_stat, k_tokT, v);

    // Stat-level top-8 selection + weights
    stat_topk<<<BB * QN, 64, 0, stream>>>(q_stat, k_stat, vlen, sel_i, sel_w);

    // Zero accumulators/counters (cnt overlays dead k_stat), bin queries
    zero_misc<<<512, 256, 0, stream>>>(out_pre, cnt);
    bin_build<<<128, 256, 0, stream>>>(sel_i, sel_w, cnt, list);

    // Token-level: 16-query chunks, 4 waves/block
    tok_fused<<<4096, 256, 0, stream>>>(q_tok, k_tokT, v, cnt, list, sel_w, out_pre);

    // Output projection
    proj_out<<<64, 256, 0, stream>>>(out_pre, Wo, (float*)d_out);
}

// Round 5
// 490.870 us; speedup vs baseline: 1.0922x; 1.0922x over previous
//
#include <hip/hip_runtime.h>
#include <hip/hip_bf16.h>
#include <math.h>

// Problem constants (from setup_inputs)
#define BB 8
#define QN 512
#define SN 64
#define TN 128
#define DD 128
#define STAT_K 8
#define TOK_K 16
#define SCALE 0.08838834764831845f   // 1/sqrt(128)
#define NEGBIG -1e6f
#define NINF  -3.4e38f
#define SLT 17                       // score LDS row stride (odd -> ballot reads conflict-free)

typedef float f4 __attribute__((ext_vector_type(4)));
typedef unsigned long long u64;

// descending compare-exchange on floats
#define CEF(a, b) { float mx_ = fmaxf(a, b), mn_ = fminf(a, b); (a) = mx_; (b) = mn_; }

// ---------------------------------------------------------------------------
// LDS-free GEMM tile: C[128-row-block] = A @ W, W read from L1/L2 (broadcast,
// 64 KB, cache-resident). 256 threads, 8x8 per-thread tile.
// ---------------------------------------------------------------------------
__device__ __forceinline__ void proj_tile8_g(const float* __restrict__ A,
                                             const float* __restrict__ W,
                                             float* __restrict__ C,
                                             int blk, int transposed, int tid)
{
    const int tx = tid & 15;    // cols tx*4..+3 and 64+tx*4..+3
    const int ty = tid >> 4;    // rows ty*8..+7
    const size_t rowBase = (size_t)blk * 128;
    const float* Ab = A + (rowBase + ty * 8) * 128;

    float acc[8][8];
    #pragma unroll
    for (int i = 0; i < 8; ++i)
        #pragma unroll
        for (int j = 0; j < 8; ++j) acc[i][j] = 0.f;

    #pragma unroll 2
    for (int k0 = 0; k0 < 128; k0 += 4) {
        f4 a[8];
        #pragma unroll
        for (int i = 0; i < 8; ++i)
            a[i] = *(const f4*)(Ab + i * 128 + k0);        // 16-lane broadcast
        f4 wl[4], wh[4];
        #pragma unroll
        for (int kk = 0; kk < 4; ++kk) {
            wl[kk] = *(const f4*)(W + (k0 + kk) * 128 + tx * 4);
            wh[kk] = *(const f4*)(W + (k0 + kk) * 128 + 64 + tx * 4);
        }
        #pragma unroll
        for (int i = 0; i < 8; ++i)
            #pragma unroll
            for (int kk = 0; kk < 4; ++kk)
                #pragma unroll
                for (int j = 0; j < 4; ++j) {
                    acc[i][j]     = fmaf(a[i][kk], wl[kk][j], acc[i][j]);
                    acc[i][4 + j] = fmaf(a[i][kk], wh[kk][j], acc[i][4 + j]);
                }
    }

    if (!transposed) {
        #pragma unroll
        for (int i = 0; i < 8; ++i) {
            size_t row = rowBase + ty * 8 + i;
            f4 lo = {acc[i][0], acc[i][1], acc[i][2], acc[i][3]};
            f4 hi = {acc[i][4], acc[i][5], acc[i][6], acc[i][7]};
            *(f4*)&C[row * 128 + tx * 4]      = lo;
            *(f4*)&C[row * 128 + 64 + tx * 4] = hi;
        }
    } else {
        float* Cb = C + ((size_t)blk << 14);   // per-(b,s) [d][t] block
        #pragma unroll
        for (int j = 0; j < 4; ++j) {
            int clo = tx * 4 + j;
            int chi = 64 + tx * 4 + j;
            f4 v0 = {acc[0][j], acc[1][j], acc[2][j], acc[3][j]};
            f4 v1 = {acc[4][j], acc[5][j], acc[6][j], acc[7][j]};
            *(f4*)&Cb[clo * 128 + ty * 8]     = v0;
            *(f4*)&Cb[clo * 128 + ty * 8 + 4] = v1;
            f4 v2 = {acc[0][4 + j], acc[1][4 + j], acc[2][4 + j], acc[3][4 + j]};
            f4 v3 = {acc[4][4 + j], acc[5][4 + j], acc[6][4 + j], acc[7][4 + j]};
            *(f4*)&Cb[chi * 128 + ty * 8]     = v2;
            *(f4*)&Cb[chi * 128 + ty * 8 + 4] = v3;
        }
    }
}

// All five input projections in one launch (big ones first).
__global__ __launch_bounds__(256) void proj_all(const float* __restrict__ queries,
                                                const float* __restrict__ stat_keys,
                                                const float* __restrict__ token_keys,
                                                const float* __restrict__ values,
                                                const float* __restrict__ Wq_stat,
                                                const float* __restrict__ Wq_token,
                                                const float* __restrict__ Wk_stat,
                                                const float* __restrict__ Wk_token,
                                                const float* __restrict__ Wv,
                                                float* __restrict__ q_stat,
                                                float* __restrict__ q_tok,
                                                float* __restrict__ k_stat,
                                                float* __restrict__ kT,
                                                float* __restrict__ v)
{
    const int bi = blockIdx.x;
    if (bi < 512)        proj_tile8_g(token_keys, Wk_token, kT,     bi,        1, threadIdx.x);
    else if (bi < 1024)  proj_tile8_g(values,     Wv,       v,      bi - 512,  0, threadIdx.x);
    else if (bi < 1056)  proj_tile8_g(queries,    Wq_stat,  q_stat, bi - 1024, 0, threadIdx.x);
    else if (bi < 1088)  proj_tile8_g(queries,    Wq_token, q_tok,  bi - 1056, 0, threadIdx.x);
    else                 proj_tile8_g(stat_keys,  Wk_stat,  k_stat, bi - 1088, 0, threadIdx.x);
}

// Output projection, 64 rows/block (small tail kernel -> more blocks).
__global__ __launch_bounds__(256) void proj_out(const float* __restrict__ A,
                                                const float* __restrict__ W,
                                                float* __restrict__ C)
{
    const int tid = threadIdx.x;
    const int tx = tid & 15;
    const int ty = tid >> 4;
    const int rowBase = blockIdx.x * 64 + ty * 4;
    const float* Ab = A + (size_t)rowBase * 128;

    float acc[4][8];
    #pragma unroll
    for (int i = 0; i < 4; ++i)
        #pragma unroll
        for (int j = 0; j < 8; ++j) acc[i][j] = 0.f;

    #pragma unroll 2
    for (int k0 = 0; k0 < 128; k0 += 4) {
        f4 a[4];
        #pragma unroll
        for (int i = 0; i < 4; ++i)
            a[i] = *(const f4*)(Ab + i * 128 + k0);
        f4 wl[4], wh[4];
        #pragma unroll
        for (int kk = 0; kk < 4; ++kk) {
            wl[kk] = *(const f4*)(W + (k0 + kk) * 128 + tx * 4);
            wh[kk] = *(const f4*)(W + (k0 + kk) * 128 + 64 + tx * 4);
        }
        #pragma unroll
        for (int i = 0; i < 4; ++i)
            #pragma unroll
            for (int kk = 0; kk < 4; ++kk)
                #pragma unroll
                for (int j = 0; j < 4; ++j) {
                    acc[i][j]     = fmaf(a[i][kk], wl[kk][j], acc[i][j]);
                    acc[i][4 + j] = fmaf(a[i][kk], wh[kk][j], acc[i][4 + j]);
                }
    }
    #pragma unroll
    for (int i = 0; i < 4; ++i) {
        size_t row = (size_t)rowBase + i;
        f4 lo = {acc[i][0], acc[i][1], acc[i][2], acc[i][3]};
        f4 hi = {acc[i][4], acc[i][5], acc[i][6], acc[i][7]};
        *(f4*)&C[row * 128 + tx * 4]      = lo;
        *(f4*)&C[row * 128 + 64 + tx * 4] = hi;
    }
}

// ---------------------------------------------------------------------------
// Stat level: one wave per (b,q), lane = stat s. Top-8 + softmax (exact jax
// tie-break: lowest index). Invalid stats -> exp underflows to exactly 0.
// ---------------------------------------------------------------------------
__global__ __launch_bounds__(64, 4) void stat_topk(const float* __restrict__ qs,
                                                   const float* __restrict__ ks,
                                                   const int* __restrict__ vlen,
                                                   int* __restrict__ sel_i,
                                                   float* __restrict__ sel_w)
{
    const int bq   = blockIdx.x;
    const int b    = bq >> 9;
    const int lane = threadIdx.x;

    const f4* q4 = (const f4*)(qs + (size_t)bq * 128);
    const f4* k4 = (const f4*)(ks + (size_t)(b * SN + lane) * 128);
    float acc = 0.f;
    #pragma unroll 8
    for (int kk = 0; kk < 32; ++kk) {
        f4 q = q4[kk];
        f4 k = k4[kk];
        acc = fmaf(q[0], k[0], acc);
        acc = fmaf(q[1], k[1], acc);
        acc = fmaf(q[2], k[2], acc);
        acc = fmaf(q[3], k[3], acc);
    }
    float score = acc * SCALE;
    if (lane >= vlen[b]) score = NEGBIG;

    float work = score;
    float tv[STAT_K];
    int   ti[STAT_K];
    #pragma unroll
    for (int j = 0; j < STAT_K; ++j) {
        float m = work;
        #pragma unroll
        for (int off = 32; off > 0; off >>= 1) m = fmaxf(m, __shfl_xor(m, off));
        unsigned long long ball = __ballot(work == m);
        int L = __ffsll(ball) - 1;     // lowest index wins ties
        tv[j] = m;
        ti[j] = L;
        if (lane == L) work = NINF;
    }

    float w[STAT_K];
    float Z = 0.f;
    #pragma unroll
    for (int j = 0; j < STAT_K; ++j) { w[j] = expf(tv[j] - tv[0]); Z += w[j]; }
    float invZ = 1.f / Z;

    if (lane < STAT_K) {
        sel_i[(size_t)bq * STAT_K + lane] = ti[lane];
        sel_w[(size_t)bq * STAT_K + lane] = w[lane] * invZ;
    }
}

// ---------------------------------------------------------------------------
__global__ void zero_misc(float* __restrict__ out_pre, int* __restrict__ cnt)
{
    int idx = blockIdx.x * 256 + threadIdx.x;    // 512*256 = 131072 f4 = 2 MB
    f4 z = {0.f, 0.f, 0.f, 0.f};
    ((f4*)out_pre)[idx] = z;
    if (idx < BB * SN) cnt[idx] = 0;
}

__global__ void bin_build(const int* __restrict__ sel_i,
                          const float* __restrict__ sel_w,
                          int* __restrict__ cnt, int* __restrict__ list)
{
    int idx = blockIdx.x * 256 + threadIdx.x;    // bq*8+si, 32768 total
    if (idx >= BB * QN * STAT_K) return;
    float sw = sel_w[idx];
    if (sw == 0.f) return;                       // exactly-zero contribution
    int bq = idx >> 3, si = idx & 7;
    int b = bq >> 9, q = bq & 511;
    int s = sel_i[idx];
    int bs = b * SN + s;
    int pos = atomicAdd(&cnt[bs], 1);
    list[bs * 512 + pos] = q | (si << 16);
}

// ---------------------------------------------------------------------------
// Token level v5: 4 waves/block, wave = 16-query chunk of one (b,s) bin.
// A: GEMM scores (k from L2, no LDS stage) -> LDS [t][q] stride-17.
// B: lane=(q,g): values-only top-16 insertion over 32 tokens (tv[16] floats),
//    2-level bitonic merge across g -> tau/m/Z (exact jax multiset).
// B2: per-q selection masks via ballots: {s>tau} + first-(16-c) ties in
//     index order (exact jax tie-break). Wave-uniform, no index arrays.
// C: lane=(q,d-quarter): walk mask bits, w=exp(s-m)*sw/Z, gather v f4,
//    atomicAdd. No u64 register arrays anywhere -> no scratch spills.
// ---------------------------------------------------------------------------
struct WaveLds {
    float sl[128 * SLT];    // scores [t][q]
    float tauA[16];
    float mA[16];
    float csA[16];
    int   qrowA[16];
    u64   msk0[16];
    u64   msk1[16];
};

__global__ __launch_bounds__(256) void tok_fused(const float* __restrict__ qt,
                                                 const float* __restrict__ kT,
                                                 const float* __restrict__ v,
                                                 const int* __restrict__ cnt,
                                                 const int* __restrict__ list,
                                                 const float* __restrict__ sel_w,
                                                 float* __restrict__ out_pre)
{
    const int bin = blockIdx.x & 511;
    const int cg  = blockIdx.x >> 9;       // 0..7
    const int b   = bin & 7;               // batch fast -> XCD spread
    const int s   = bin >> 3;
    const int bs  = b * SN + s;
    const int nq  = cnt[bs];

    const int tid  = threadIdx.x;
    const int wid  = tid >> 6;
    const int lane = tid & 63;
    const int q0   = (cg * 4 + wid) * 16;
    if (q0 >= nq) return;                  // no __syncthreads anywhere: safe
    const int nhere = min(16, nq - q0);

    __shared__ WaveLds wlds[4];            // ~36.6 KB total
    WaveLds& W = wlds[wid];

    // ---- Phase A: GEMM scores ----
    const int qg = lane >> 5;              // 8-query group
    const int tg = lane & 31;              // tokens tg*4..tg*4+3
    const float* kb = kT + ((size_t)bs << 14);

    {
        int qrow[8];
        #pragma unroll
        for (int i = 0; i < 8; ++i) {
            int e = list[bs * 512 + min(q0 + qg * 8 + i, nq - 1)];  // clamp: dup
            qrow[i] = e & 0xffff;
        }
        float acc[8][4];
        #pragma unroll
        for (int i = 0; i < 8; ++i)
            #pragma unroll
            for (int j = 0; j < 4; ++j) acc[i][j] = 0.f;

        #pragma unroll 2
        for (int dq = 0; dq < 128; dq += 4) {
            f4 kf[4];
            #pragma unroll
            for (int kk = 0; kk < 4; ++kk)
                kf[kk] = *(const f4*)(kb + (size_t)(dq + kk) * 128 + tg * 4);
            f4 qv[8];
            #pragma unroll
            for (int i = 0; i < 8; ++i)
                qv[i] = *(const f4*)(qt + ((size_t)(b * QN + qrow[i])) * 128 + dq);
            #pragma unroll
            for (int i = 0; i < 8; ++i)
                #pragma unroll
                for (int kk = 0; kk < 4; ++kk)
                    #pragma unroll
                    for (int j = 0; j < 4; ++j)
                        acc[i][j] = fmaf(qv[i][kk], kf[kk][j], acc[i][j]);
        }
        #pragma unroll
        for (int i = 0; i < 8; ++i)
            #pragma unroll
            for (int j = 0; j < 4; ++j)
                W.sl[(tg * 4 + j) * SLT + qg * 8 + i] = acc[i][j] * SCALE;
    }

    __asm__ __volatile__("" ::: "memory");
    __builtin_amdgcn_wave_barrier();
    __asm__ __volatile__("" ::: "memory");

    // ---- Phase B: values-only top-16 ----
    const int q = lane & 15;
    const int g = lane >> 4;               // 32-token group

    {
        float tv[16];
        #pragma unroll
        for (int j = 0; j < 16; ++j) tv[j] = NINF;

        #pragma unroll 4
        for (int i = 0; i < 32; ++i) {
            float x = W.sl[(g * 32 + i) * SLT + q];
            #pragma unroll
            for (int j = 0; j < 16; ++j) {
                float hi = fmaxf(tv[j], x);
                x = fminf(tv[j], x);
                tv[j] = hi;
            }
        }
        // merge across g: lane xor 16 (g^1), then xor 32 (g^2)
        #pragma unroll
        for (int lev = 0; lev < 2; ++lev) {
            const int d = 16 << lev;
            float ov[16];
            #pragma unroll
            for (int j = 0; j < 16; ++j) ov[j] = __shfl_xor(tv[j], d);
            #pragma unroll
            for (int j = 0; j < 16; ++j) tv[j] = fmaxf(tv[j], ov[15 - j]);
            #pragma unroll
            for (int j = 0; j < 16; ++j) if (!(j & 8)) CEF(tv[j], tv[j + 8]);
            #pragma unroll
            for (int j = 0; j < 16; ++j) if (!(j & 4)) CEF(tv[j], tv[j + 4]);
            #pragma unroll
            for (int j = 0; j < 16; ++j) if (!(j & 2)) CEF(tv[j], tv[j + 2]);
            #pragma unroll
            for (int j = 0; j < 16; ++j) if (!(j & 1)) CEF(tv[j], tv[j + 1]);
        }
        if (g == 0) {
            float m = tv[0];
            float Z = 0.f;
            #pragma unroll
            for (int j = 0; j < 16; ++j) Z += expf(tv[j] - m);
            int e = list[bs * 512 + min(q0 + q, nq - 1)];
            int qr  = e & 0xffff;
            int si  = (e >> 16) & 7;
            float sw = sel_w[((size_t)(b * QN + qr)) * STAT_K + si];
            W.tauA[q]  = tv[15];
            W.mA[q]    = m;
            W.csA[q]   = sw / Z;
            W.qrowA[q] = qr;
        }
    }

    __asm__ __volatile__("" ::: "memory");
    __builtin_amdgcn_wave_barrier();
    __asm__ __volatile__("" ::: "memory");

    // ---- Phase B2: selection masks per q (ballots; exact tie budget) ----
    for (int qq = 0; qq < 16; ++qq) {
        float tau = W.tauA[qq];
        float s0 = W.sl[lane * SLT + qq];              // stride 17: conflict-free
        float s1 = W.sl[(lane + 64) * SLT + qq];
        u64 b0 = __ballot(s0 > tau);
        u64 b1 = __ballot(s1 > tau);
        u64 t0 = __ballot(s0 == tau);
        u64 t1 = __ballot(s1 == tau);
        int r = 16 - __popcll(b0) - __popcll(b1);      // wave-uniform
        u64 k0 = 0, k1 = 0;
        while (r > 0 && t0) { u64 lb = t0 & (~t0 + 1ull); k0 |= lb; t0 ^= lb; --r; }
        while (r > 0 && t1) { u64 lb = t1 & (~t1 + 1ull); k1 |= lb; t1 ^= lb; --r; }
        if (lane == 0) { W.msk0[qq] = b0 | k0; W.msk1[qq] = b1 | k1; }
    }

    __asm__ __volatile__("" ::: "memory");
    __builtin_amdgcn_wave_barrier();
    __asm__ __volatile__("" ::: "memory");

    // ---- Phase C: PV gather, lane = (q, d-quarter g) ----
    if (q < nhere) {
        float m  = W.mA[q];
        float cs = W.csA[q];
        int   qr = W.qrowA[q];
        u64 m0 = W.msk0[q];
        u64 m1 = W.msk1[q];
        const float* vb = v + ((size_t)bs << 14) + g * 32;

        f4 o[8];
        #pragma unroll
        for (int c = 0; c < 8; ++c) o[c] = (f4){0.f, 0.f, 0.f, 0.f};

        while (m0) {
            int t = __ffsll(m0) - 1; m0 &= m0 - 1;
            float w = expf(W.sl[t * SLT + q] - m) * cs;
            const f4* vr = (const f4*)(vb + (size_t)t * 128);
            #pragma unroll
            for (int c = 0; c < 8; ++c) {
                f4 x = vr[c];
                o[c][0] = fmaf(w, x[0], o[c][0]);
                o[c][1] = fmaf(w, x[1], o[c][1]);
                o[c][2] = fmaf(w, x[2], o[c][2]);
                o[c][3] = fmaf(w, x[3], o[c][3]);
            }
        }
        while (m1) {
            int t = __ffsll(m1) - 1; m1 &= m1 - 1;
            float w = expf(W.sl[(t + 64) * SLT + q] - m) * cs;
            const f4* vr = (const f4*)(vb + (size_t)(t + 64) * 128);
            #pragma unroll
            for (int c = 0; c < 8; ++c) {
                f4 x = vr[c];
                o[c][0] = fmaf(w, x[0], o[c][0]);
                o[c][1] = fmaf(w, x[1], o[c][1]);
                o[c][2] = fmaf(w, x[2], o[c][2]);
                o[c][3] = fmaf(w, x[3], o[c][3]);
            }
        }

        float* op = out_pre + ((size_t)(b * QN + qr)) * 128 + g * 32;
        #pragma unroll
        for (int c = 0; c < 8; ++c) {
            atomicAdd(op + c * 4 + 0, o[c][0]);
            atomicAdd(op + c * 4 + 1, o[c][1]);
            atomicAdd(op + c * 4 + 2, o[c][2]);
            atomicAdd(op + c * 4 + 3, o[c][3]);
        }
    }
}

// ---------------------------------------------------------------------------
extern "C" void kernel_launch(void* const* d_in, const int* in_sizes, int n_in,
                              void* d_out, int out_size, void* d_ws, size_t ws_size,
                              hipStream_t stream)
{
    const float* queries    = (const float*)d_in[0];
    const float* stat_keys  = (const float*)d_in[1];
    const float* token_keys = (const float*)d_in[2];
    const float* values     = (const float*)d_in[3];
    const int*   vlen       = (const int*)d_in[4];
    const float* Wq_stat    = (const float*)d_in[5];
    const float* Wq_token   = (const float*)d_in[6];
    const float* Wk_stat    = (const float*)d_in[7];
    const float* Wk_token   = (const float*)d_in[8];
    const float* Wv         = (const float*)d_in[9];
    const float* Wo         = (const float*)d_in[10];

    char* ws = (char*)d_ws;
    float* q_stat  = (float*)(ws);                 // 2 MB (dead after stat_topk)
    int*   list    = (int*)  (ws);                 // 1 MB, overlays q_stat
    float* q_tok   = (float*)(ws + 2097152);       // 2 MB
    float* k_stat  = (float*)(ws + 4194304);       // 256 KB (dead after stat_topk)
    int*   cnt     = (int*)  (ws + 4194304);       // 2 KB, overlays k_stat
    float* k_tokT  = (float*)(ws + 4456448);       // [512][128d][128t] = 32 MB
    float* v       = (float*)(ws + 38010880);      // 32 MB
    int*   sel_i   = (int*)  (ws + 71565312);      // 128 KB
    float* sel_w   = (float*)(ws + 71696384);      // 128 KB
    float* out_pre = (float*)(ws + 71827456);      // 2 MB  (total 73,924,608 B)

    // All input projections (fp32 exact: scores feed top-k), one launch
    proj_all<<<1092, 256, 0, stream>>>(queries, stat_keys, token_keys, values,
                                       Wq_stat, Wq_token, Wk_stat, Wk_token, Wv,
                                       q_stat, q_tok, k_stat, k_tokT, v);

    // Stat-level top-8 selection + weights
    stat_topk<<<BB * QN, 64, 0, stream>>>(q_stat, k_stat, vlen, sel_i, sel_w);

    // Zero accumulators/counters (cnt overlays dead k_stat), bin queries
    zero_misc<<<512, 256, 0, stream>>>(out_pre, cnt);
    bin_build<<<128, 256, 0, stream>>>(sel_i, sel_w, cnt, list);

    // Token-level: 16-query chunks, 4 waves/block, values-only selection
    tok_fused<<<4096, 256, 0, stream>>>(q_tok, k_tokT, v, cnt, list, sel_w, out_pre);

    // Output projection
    proj_out<<<64, 256, 0, stream>>>(out_pre, Wo, (float*)d_out);
}

// Round 6
// 310.884 us; speedup vs baseline: 1.7245x; 1.5789x over previous
//
#include <hip/hip_runtime.h>
#include <hip/hip_bf16.h>
#include <math.h>

// Problem constants (from setup_inputs)
#define BB 8
#define QN 512
#define SN 64
#define TN 128
#define DD 128
#define STAT_K 8
#define TOK_K 16
#define SCALE 0.08838834764831845f   // 1/sqrt(128)
#define NEGBIG -1e6f
#define NINF  -3.4e38f

typedef float f4 __attribute__((ext_vector_type(4)));
typedef float f2 __attribute__((ext_vector_type(2)));
typedef unsigned long long u64;

// ---------------------------------------------------------------------------
// LDS-free GEMM tile: C[128-row-block] = A @ W, W read from L1/L2 (broadcast,
// 64 KB, cache-resident). 256 threads, 8x8 per-thread tile. (proven R3-R5)
// ---------------------------------------------------------------------------
__device__ __forceinline__ void proj_tile8_g(const float* __restrict__ A,
                                             const float* __restrict__ W,
                                             float* __restrict__ C,
                                             int blk, int transposed, int tid)
{
    const int tx = tid & 15;    // cols tx*4..+3 and 64+tx*4..+3
    const int ty = tid >> 4;    // rows ty*8..+7
    const size_t rowBase = (size_t)blk * 128;
    const float* Ab = A + (rowBase + ty * 8) * 128;

    float acc[8][8];
    #pragma unroll
    for (int i = 0; i < 8; ++i)
        #pragma unroll
        for (int j = 0; j < 8; ++j) acc[i][j] = 0.f;

    #pragma unroll 2
    for (int k0 = 0; k0 < 128; k0 += 4) {
        f4 a[8];
        #pragma unroll
        for (int i = 0; i < 8; ++i)
            a[i] = *(const f4*)(Ab + i * 128 + k0);        // 16-lane broadcast
        f4 wl[4], wh[4];
        #pragma unroll
        for (int kk = 0; kk < 4; ++kk) {
            wl[kk] = *(const f4*)(W + (k0 + kk) * 128 + tx * 4);
            wh[kk] = *(const f4*)(W + (k0 + kk) * 128 + 64 + tx * 4);
        }
        #pragma unroll
        for (int i = 0; i < 8; ++i)
            #pragma unroll
            for (int kk = 0; kk < 4; ++kk)
                #pragma unroll
                for (int j = 0; j < 4; ++j) {
                    acc[i][j]     = fmaf(a[i][kk], wl[kk][j], acc[i][j]);
                    acc[i][4 + j] = fmaf(a[i][kk], wh[kk][j], acc[i][4 + j]);
                }
    }

    if (!transposed) {
        #pragma unroll
        for (int i = 0; i < 8; ++i) {
            size_t row = rowBase + ty * 8 + i;
            f4 lo = {acc[i][0], acc[i][1], acc[i][2], acc[i][3]};
            f4 hi = {acc[i][4], acc[i][5], acc[i][6], acc[i][7]};
            *(f4*)&C[row * 128 + tx * 4]      = lo;
            *(f4*)&C[row * 128 + 64 + tx * 4] = hi;
        }
    } else {
        float* Cb = C + ((size_t)blk << 14);   // per-(b,s) [d][t] block
        #pragma unroll
        for (int j = 0; j < 4; ++j) {
            int clo = tx * 4 + j;
            int chi = 64 + tx * 4 + j;
            f4 v0 = {acc[0][j], acc[1][j], acc[2][j], acc[3][j]};
            f4 v1 = {acc[4][j], acc[5][j], acc[6][j], acc[7][j]};
            *(f4*)&Cb[clo * 128 + ty * 8]     = v0;
            *(f4*)&Cb[clo * 128 + ty * 8 + 4] = v1;
            f4 v2 = {acc[0][4 + j], acc[1][4 + j], acc[2][4 + j], acc[3][4 + j]};
            f4 v3 = {acc[4][4 + j], acc[5][4 + j], acc[6][4 + j], acc[7][4 + j]};
            *(f4*)&Cb[chi * 128 + ty * 8]     = v2;
            *(f4*)&Cb[chi * 128 + ty * 8 + 4] = v3;
        }
    }
}

// All five input projections in one launch (big ones first).
__global__ __launch_bounds__(256) void proj_all(const float* __restrict__ queries,
                                                const float* __restrict__ stat_keys,
                                                const float* __restrict__ token_keys,
                                                const float* __restrict__ values,
                                                const float* __restrict__ Wq_stat,
                                                const float* __restrict__ Wq_token,
                                                const float* __restrict__ Wk_stat,
                                                const float* __restrict__ Wk_token,
                                                const float* __restrict__ Wv,
                                                float* __restrict__ q_stat,
                                                float* __restrict__ q_tok,
                                                float* __restrict__ k_stat,
                                                float* __restrict__ kT,
                                                float* __restrict__ v)
{
    const int bi = blockIdx.x;
    if (bi < 512)        proj_tile8_g(token_keys, Wk_token, kT,     bi,        1, threadIdx.x);
    else if (bi < 1024)  proj_tile8_g(values,     Wv,       v,      bi - 512,  0, threadIdx.x);
    else if (bi < 1056)  proj_tile8_g(queries,    Wq_stat,  q_stat, bi - 1024, 0, threadIdx.x);
    else if (bi < 1088)  proj_tile8_g(queries,    Wq_token, q_tok,  bi - 1056, 0, threadIdx.x);
    else                 proj_tile8_g(stat_keys,  Wk_stat,  k_stat, bi - 1088, 0, threadIdx.x);
}

// Output projection, 64 rows/block.
__global__ __launch_bounds__(256) void proj_out(const float* __restrict__ A,
                                                const float* __restrict__ W,
                                                float* __restrict__ C)
{
    const int tid = threadIdx.x;
    const int tx = tid & 15;
    const int ty = tid >> 4;
    const int rowBase = blockIdx.x * 64 + ty * 4;
    const float* Ab = A + (size_t)rowBase * 128;

    float acc[4][8];
    #pragma unroll
    for (int i = 0; i < 4; ++i)
        #pragma unroll
        for (int j = 0; j < 8; ++j) acc[i][j] = 0.f;

    #pragma unroll 2
    for (int k0 = 0; k0 < 128; k0 += 4) {
        f4 a[4];
        #pragma unroll
        for (int i = 0; i < 4; ++i)
            a[i] = *(const f4*)(Ab + i * 128 + k0);
        f4 wl[4], wh[4];
        #pragma unroll
        for (int kk = 0; kk < 4; ++kk) {
            wl[kk] = *(const f4*)(W + (k0 + kk) * 128 + tx * 4);
            wh[kk] = *(const f4*)(W + (k0 + kk) * 128 + 64 + tx * 4);
        }
        #pragma unroll
        for (int i = 0; i < 4; ++i)
            #pragma unroll
            for (int kk = 0; kk < 4; ++kk)
                #pragma unroll
                for (int j = 0; j < 4; ++j) {
                    acc[i][j]     = fmaf(a[i][kk], wl[kk][j], acc[i][j]);
                    acc[i][4 + j] = fmaf(a[i][kk], wh[kk][j], acc[i][4 + j]);
                }
    }
    #pragma unroll
    for (int i = 0; i < 4; ++i) {
        size_t row = (size_t)rowBase + i;
        f4 lo = {acc[i][0], acc[i][1], acc[i][2], acc[i][3]};
        f4 hi = {acc[i][4], acc[i][5], acc[i][6], acc[i][7]};
        *(f4*)&C[row * 128 + tx * 4]      = lo;
        *(f4*)&C[row * 128 + 64 + tx * 4] = hi;
    }
}

// ---------------------------------------------------------------------------
// Stat level: one wave per (b,q), lane = stat s. Top-8 + softmax (exact jax
// tie-break). Invalid stats -> exp underflows to exactly 0. (proven R1)
// ---------------------------------------------------------------------------
__global__ __launch_bounds__(64, 4) void stat_topk(const float* __restrict__ qs,
                                                   const float* __restrict__ ks,
                                                   const int* __restrict__ vlen,
                                                   int* __restrict__ sel_i,
                                                   float* __restrict__ sel_w)
{
    const int bq   = blockIdx.x;
    const int b    = bq >> 9;
    const int lane = threadIdx.x;

    const f4* q4 = (const f4*)(qs + (size_t)bq * 128);
    const f4* k4 = (const f4*)(ks + (size_t)(b * SN + lane) * 128);
    float acc = 0.f;
    #pragma unroll 8
    for (int kk = 0; kk < 32; ++kk) {
        f4 q = q4[kk];
        f4 k = k4[kk];
        acc = fmaf(q[0], k[0], acc);
        acc = fmaf(q[1], k[1], acc);
        acc = fmaf(q[2], k[2], acc);
        acc = fmaf(q[3], k[3], acc);
    }
    float score = acc * SCALE;
    if (lane >= vlen[b]) score = NEGBIG;

    float work = score;
    float tv[STAT_K];
    int   ti[STAT_K];
    #pragma unroll
    for (int j = 0; j < STAT_K; ++j) {
        float m = work;
        #pragma unroll
        for (int off = 32; off > 0; off >>= 1) m = fmaxf(m, __shfl_xor(m, off));
        unsigned long long ball = __ballot(work == m);
        int L = __ffsll(ball) - 1;     // lowest index wins ties
        tv[j] = m;
        ti[j] = L;
        if (lane == L) work = NINF;
    }

    float w[STAT_K];
    float Z = 0.f;
    #pragma unroll
    for (int j = 0; j < STAT_K; ++j) { w[j] = expf(tv[j] - tv[0]); Z += w[j]; }
    float invZ = 1.f / Z;

    if (lane < STAT_K) {
        sel_i[(size_t)bq * STAT_K + lane] = ti[lane];
        sel_w[(size_t)bq * STAT_K + lane] = w[lane] * invZ;
    }
}

// ---------------------------------------------------------------------------
__global__ void zero_cnt(int* __restrict__ cnt)
{
    int idx = blockIdx.x * 256 + threadIdx.x;
    if (idx < BB * SN) cnt[idx] = 0;
}

__global__ void bin_build(const int* __restrict__ sel_i,
                          const float* __restrict__ sel_w,
                          int* __restrict__ cnt, int* __restrict__ list)
{
    int idx = blockIdx.x * 256 + threadIdx.x;    // bq*8+si, 32768 total
    if (idx >= BB * QN * STAT_K) return;
    float sw = sel_w[idx];
    if (sw == 0.f) return;                       // exactly-zero contribution
    int bq = idx >> 3, si = idx & 7;
    int b = bq >> 9, q = bq & 511;
    int s = sel_i[idx];
    int bs = b * SN + s;
    int pos = atomicAdd(&cnt[bs], 1);
    list[bs * 512 + pos] = q | (si << 16);
}

// ---------------------------------------------------------------------------
// K1: token scores as a plain GEMM (proven proj tile shape, acc[4][8]).
// Block = (bin, 64-pair chunk). scores[pid][t] = q_tok[bq] . kT[bs][.][t] * SCALE
// ---------------------------------------------------------------------------
__global__ __launch_bounds__(256) void tok_score(const float* __restrict__ qt,
                                                 const float* __restrict__ kT,
                                                 const int* __restrict__ cnt,
                                                 const int* __restrict__ list,
                                                 float* __restrict__ scores)
{
    const int bin   = blockIdx.x & 511;
    const int chunk = blockIdx.x >> 9;
    const int b  = bin & 7;            // batch fast -> XCD spread
    const int s  = bin >> 3;
    const int bs = b * SN + s;
    const int nq = cnt[bs];
    const int q0 = chunk * 64;
    if (q0 >= nq) return;

    const int tid = threadIdx.x;
    const int tx = tid & 15;           // t-cols tx*4..+3 and 64+tx*4..+3
    const int ty = tid >> 4;           // pair-slots q0+ty*4..+3

    int pid[4];
    const float* Ab[4];
    #pragma unroll
    for (int i = 0; i < 4; ++i) {
        int e  = list[bs * 512 + min(q0 + ty * 4 + i, nq - 1)];  // clamp: dup pair
        int q  = e & 0xffff;
        int si = (e >> 16) & 7;
        pid[i] = ((b << 9) + q) * 8 + si;
        Ab[i]  = qt + ((size_t)(b << 9) + q) * 128;
    }
    const float* kb = kT + ((size_t)bs << 14);

    float acc[4][8];
    #pragma unroll
    for (int i = 0; i < 4; ++i)
        #pragma unroll
        for (int j = 0; j < 8; ++j) acc[i][j] = 0.f;

    #pragma unroll 2
    for (int k0 = 0; k0 < 128; k0 += 4) {
        f4 a[4];
        #pragma unroll
        for (int i = 0; i < 4; ++i)
            a[i] = *(const f4*)(Ab[i] + k0);               // 16-lane broadcast
        f4 wl[4], wh[4];
        #pragma unroll
        for (int kk = 0; kk < 4; ++kk) {
            wl[kk] = *(const f4*)(kb + (size_t)(k0 + kk) * 128 + tx * 4);
            wh[kk] = *(const f4*)(kb + (size_t)(k0 + kk) * 128 + 64 + tx * 4);
        }
        #pragma unroll
        for (int i = 0; i < 4; ++i)
            #pragma unroll
            for (int kk = 0; kk < 4; ++kk)
                #pragma unroll
                for (int j = 0; j < 4; ++j) {
                    acc[i][j]     = fmaf(a[i][kk], wl[kk][j], acc[i][j]);
                    acc[i][4 + j] = fmaf(a[i][kk], wh[kk][j], acc[i][4 + j]);
                }
    }

    #pragma unroll
    for (int i = 0; i < 4; ++i) {
        float* out = scores + (size_t)pid[i] * 128;
        f4 lo = {acc[i][0] * SCALE, acc[i][1] * SCALE, acc[i][2] * SCALE, acc[i][3] * SCALE};
        f4 hi = {acc[i][4] * SCALE, acc[i][5] * SCALE, acc[i][6] * SCALE, acc[i][7] * SCALE};
        *(f4*)(out + tx * 4)      = lo;    // dup pids write identical data: benign
        *(f4*)(out + 64 + tx * 4) = hi;
    }
}

// ---------------------------------------------------------------------------
// K2: exact top-16 + softmax weights per pair. One wave per pid.
// Lane holds tokens 2*lane, 2*lane+1 -> lane order == token order (exact jax
// tie-break: lowest token index wins). R1-proven ballot-iterative selection.
// ---------------------------------------------------------------------------
__global__ __launch_bounds__(256) void tok_select(const float* __restrict__ scores,
                                                  const float* __restrict__ sel_w,
                                                  int* __restrict__ pvt,
                                                  float* __restrict__ pvw)
{
    const int pid  = blockIdx.x * 4 + (threadIdx.x >> 6);
    const int lane = threadIdx.x & 63;

    float sw = sel_w[pid];
    if (sw == 0.f) {                        // never binned: zero contribution
        if (lane < TOK_K) {
            pvt[(size_t)pid * TOK_K + lane] = 0;
            pvw[(size_t)pid * TOK_K + lane] = 0.f;
        }
        return;
    }

    f2 c = *(const f2*)(scores + (size_t)pid * 128 + lane * 2);
    float c0 = c[0], c1 = c[1];

    float tv[TOK_K];
    int   tt[TOK_K];
    #pragma unroll
    for (int j = 0; j < TOK_K; ++j) {
        float lm = fmaxf(c0, c1);
        float m = lm;
        #pragma unroll
        for (int off = 32; off > 0; off >>= 1) m = fmaxf(m, __shfl_xor(m, off));
        u64 b0 = __ballot(c0 == m);
        u64 b1 = __ballot(c1 == m);
        int L0 = b0 ? (__ffsll(b0) - 1) : 64;
        int L1 = b1 ? (__ffsll(b1) - 1) : 64;
        int t0 = 2 * L0, t1 = 2 * L1 + 1;
        int t  = min(t0, t1);               // lowest token index among ties
        tv[j] = m;
        tt[j] = t;
        if (lane == (t >> 1)) {
            if (t & 1) c1 = NINF; else c0 = NINF;
        }
    }

    float m0 = tv[0];
    float Z = 0.f;
    float pw[TOK_K];
    #pragma unroll
    for (int j = 0; j < TOK_K; ++j) { pw[j] = expf(tv[j] - m0); Z += pw[j]; }
    float cs = sw / Z;                      // fold stat weight in

    if (lane < TOK_K) {
        pvt[(size_t)pid * TOK_K + lane] = tt[lane];
        pvw[(size_t)pid * TOK_K + lane] = pw[lane] * cs;
    }
}

// ---------------------------------------------------------------------------
// K3: PV accumulate. One wave per (b,q): sum over 8 stats x 16 tokens in
// registers, single plain store (no atomics -> fully deterministic).
// ---------------------------------------------------------------------------
__global__ __launch_bounds__(256) void tok_pv2(const float* __restrict__ v,
                                               const int* __restrict__ sel_i,
                                               const int* __restrict__ pvt,
                                               const float* __restrict__ pvw,
                                               float* __restrict__ out_pre)
{
    const int bq   = blockIdx.x * 4 + (threadIdx.x >> 6);
    const int lane = threadIdx.x & 63;
    const int b    = bq >> 9;

    float o0 = 0.f, o1 = 0.f;
    #pragma unroll
    for (int si = 0; si < STAT_K; ++si) {
        const int pid = bq * STAT_K + si;
        const int s   = sel_i[pid];
        const float* vb = v + ((size_t)(b * SN + s) << 14);
        const int*   tp = pvt + (size_t)pid * TOK_K;
        const float* wp = pvw + (size_t)pid * TOK_K;
        #pragma unroll
        for (int j = 0; j < TOK_K; ++j) {
            int   t = tp[j];                 // wave-uniform
            float w = wp[j];                 // ==0 for skipped pids: exact no-op
            f2 x = *(const f2*)(vb + (size_t)t * 128 + lane * 2);
            o0 = fmaf(w, x[0], o0);
            o1 = fmaf(w, x[1], o1);
        }
    }
    f2 o = {o0, o1};
    *(f2*)(out_pre + (size_t)bq * 128 + lane * 2) = o;
}

// ---------------------------------------------------------------------------
extern "C" void kernel_launch(void* const* d_in, const int* in_sizes, int n_in,
                              void* d_out, int out_size, void* d_ws, size_t ws_size,
                              hipStream_t stream)
{
    const float* queries    = (const float*)d_in[0];
    const float* stat_keys  = (const float*)d_in[1];
    const float* token_keys = (const float*)d_in[2];
    const float* values     = (const float*)d_in[3];
    const int*   vlen       = (const int*)d_in[4];
    const float* Wq_stat    = (const float*)d_in[5];
    const float* Wq_token   = (const float*)d_in[6];
    const float* Wk_stat    = (const float*)d_in[7];
    const float* Wk_token   = (const float*)d_in[8];
    const float* Wv         = (const float*)d_in[9];
    const float* Wo         = (const float*)d_in[10];

    char* ws = (char*)d_ws;
    float* q_stat  = (float*)(ws);                 // 2 MB (dead after stat_topk)
    int*   list    = (int*)  (ws);                 // 1 MB, overlays q_stat
    float* q_tok   = (float*)(ws + 2097152);       // 2 MB (dead after tok_score)
    float* k_stat  = (float*)(ws + 4194304);       // 256 KB (dead after stat_topk)
    int*   cnt     = (int*)  (ws + 4194304);       // 2 KB, overlays k_stat
    float* k_tokT  = (float*)(ws + 4456448);       // 32 MB (dead after tok_score)
    int*   pvt     = (int*)  (ws + 4456448);       // 2 MB, overlays k_tokT
    float* pvw     = (float*)(ws + 6553600);       // 2 MB, overlays k_tokT
    float* out_pre = (float*)(ws + 8650752);       // 2 MB, overlays k_tokT
    float* v       = (float*)(ws + 38010880);      // 32 MB (live till tok_pv2)
    int*   sel_i   = (int*)  (ws + 71565312);      // 128 KB
    float* sel_w   = (float*)(ws + 71696384);      // 128 KB
    float* scores  = (float*)(ws + 71827456);      // 16 MB (32768*128*4)
                                                   // total 88,604,672 B

    // All input projections (fp32 exact: scores feed top-k), one launch
    proj_all<<<1092, 256, 0, stream>>>(queries, stat_keys, token_keys, values,
                                       Wq_stat, Wq_token, Wk_stat, Wk_token, Wv,
                                       q_stat, q_tok, k_stat, k_tokT, v);

    // Stat-level top-8 selection + weights
    stat_topk<<<BB * QN, 64, 0, stream>>>(q_stat, k_stat, vlen, sel_i, sel_w);

    // Zero bin counters (overlays dead k_stat), bin (q,si) pairs by stat
    zero_cnt<<<2, 256, 0, stream>>>(cnt);
    bin_build<<<128, 256, 0, stream>>>(sel_i, sel_w, cnt, list);

    // K1: token scores (GEMM shape, k read once per chunk from L2)
    tok_score<<<4096, 256, 0, stream>>>(q_tok, k_tokT, cnt, list, scores);

    // K2: exact top-16 + folded softmax weights, one wave per pair
    tok_select<<<BB * QN * STAT_K / 4, 256, 0, stream>>>(scores, sel_w, pvt, pvw);

    // K3: PV accumulate, one wave per (b,q), no atomics
    tok_pv2<<<BB * QN / 4, 256, 0, stream>>>(v, sel_i, pvt, pvw, out_pre);

    // Output projection
    proj_out<<<64, 256, 0, stream>>>(out_pre, Wo, (float*)d_out);
}